// Round 5
// baseline (205.408 us; speedup 1.0000x reference)
//
#include <hip/hip_runtime.h>
#include <hip/hip_bf16.h>

typedef __attribute__((ext_vector_type(4))) float f32x4;
typedef __attribute__((ext_vector_type(8))) short s16x8;
typedef unsigned long long u64;

#define NB_ 4
#define N_ 4096
#define FI_ 256
#define FO_ 128
#define NROWS 16384       // NB_ * N_
#define SPLIT 4
#define NSTEPS ((N_ / SPLIT) / 32)   // 32 steps of 32 cols

// pack two f32 -> one u32 of 2 bf16 (RNE), first arg in low half
__device__ __forceinline__ unsigned pkbf(float a, float b) {
    __hip_bfloat162 t = __float22bfloat162_rn(make_float2(a, b));
    unsigned r; __builtin_memcpy(&r, &t, 4); return r;
}

// ---------------- K_adjb: adj (268MB) -> bitmask (8.4MB), pure stream ----
__global__ __launch_bounds__(256) void k_adjb(
    const int* __restrict__ adj, u64* __restrict__ bits)
{
    const int t = threadIdx.x;
    const int w = t >> 6, l = t & 63;
    const int row = blockIdx.x * 4 + w;                  // 0..16383
    const int* ar = adj + (size_t)row * N_;
    u64* br = bits + (size_t)row * 64;
    #pragma unroll 2
    for (int s = 0; s < 64; s += 4) {
        int v0 = ar[(s + 0) * 64 + l];
        int v1 = ar[(s + 1) * 64 + l];
        int v2 = ar[(s + 2) * 64 + l];
        int v3 = ar[(s + 3) * 64 + l];
        u64 b0 = __ballot(v0 > 0);
        u64 b1 = __ballot(v1 > 0);
        u64 b2 = __ballot(v2 > 0);
        u64 b3 = __ballot(v3 > 0);
        if (l == 0) { br[s] = b0; br[s + 1] = b1; br[s + 2] = b2; br[s + 3] = b3; }
    }
}

// ---------------- K0: pack W into bf16 hi/lo ----------------------------
__global__ __launch_bounds__(256) void k0_packw(
    const float* __restrict__ Ww, __hip_bfloat16* __restrict__ whi,
    __hip_bfloat16* __restrict__ wlo)
{
    int idx = blockIdx.x * 256 + threadIdx.x;           // 32768 elems
    float v = Ww[idx];
    __hip_bfloat16 hi = __float2bfloat16(v);
    whi[idx] = hi;
    wlo[idx] = __float2bfloat16(v - __bfloat162float(hi));
}

// ---------------- K1: Wh = h @ W^T + Wb  (split-bf16, 3 MFMA) -----------
__global__ __launch_bounds__(256) void k1_wh(
    const float* __restrict__ h, const __hip_bfloat16* __restrict__ whi,
    const __hip_bfloat16* __restrict__ wlo, const float* __restrict__ Wb,
    float* __restrict__ Wh)
{
    const int tid = threadIdx.x;
    const int w = tid >> 6, l = tid & 63;
    const int lr = l & 15, g = l >> 4;
    const int r0 = blockIdx.x * 16;
    const float* hp = h + (size_t)(r0 + lr) * FI_ + g * 8;

    f32x4 acc[2] = {(f32x4)0.f, (f32x4)0.f};

    #pragma unroll
    for (int kt = 0; kt < 8; ++kt) {
        f32x4 x0 = *(const f32x4*)(hp + kt * 32);
        f32x4 x1 = *(const f32x4*)(hp + kt * 32 + 4);
        float xx[8];
        #pragma unroll
        for (int t = 0; t < 4; ++t) { xx[t] = x0[t]; xx[t + 4] = x1[t]; }
        union { s16x8 v; unsigned u[4]; } ahi, alo;
        #pragma unroll
        for (int t = 0; t < 4; ++t) {
            float a0 = xx[2 * t], a1 = xx[2 * t + 1];
            unsigned uh = pkbf(a0, a1);
            ahi.u[t] = uh;
            float h0f = __uint_as_float(uh << 16);
            float h1f = __uint_as_float(uh & 0xffff0000u);
            alo.u[t] = pkbf(a0 - h0f, a1 - h1f);
        }
        #pragma unroll
        for (int c = 0; c < 2; ++c) {
            const int o = w * 32 + c * 16 + lr;
            s16x8 bh = *(const s16x8*)(whi + (size_t)o * FI_ + kt * 32 + g * 8);
            s16x8 bl = *(const s16x8*)(wlo + (size_t)o * FI_ + kt * 32 + g * 8);
            acc[c] = __builtin_amdgcn_mfma_f32_16x16x32_bf16(ahi.v, bh, acc[c], 0, 0, 0);
            acc[c] = __builtin_amdgcn_mfma_f32_16x16x32_bf16(alo.v, bh, acc[c], 0, 0, 0);
            acc[c] = __builtin_amdgcn_mfma_f32_16x16x32_bf16(ahi.v, bl, acc[c], 0, 0, 0);
        }
    }

    #pragma unroll
    for (int c = 0; c < 2; ++c) {
        int col = w * 32 + c * 16 + lr;
        float wb = Wb[col];
        #pragma unroll
        for (int kk = 0; kk < 4; ++kk) {
            int grow = r0 + g * 4 + kk;
            Wh[(size_t)grow * FO_ + col] = acc[c][kk] + wb;
        }
    }
}

// ---------------- K1t: transpose Wh -> WhT bf16 [b][o][n] ---------------
__global__ __launch_bounds__(256) void k1t(
    const float* __restrict__ Wh, __hip_bfloat16* __restrict__ WhT)
{
    __shared__ __hip_bfloat16 lds[64][130];
    const int t = threadIdx.x;
    const int r0 = blockIdx.x * 64;                      // 256 blocks
    {
        int row = t >> 2, cs = (t & 3) * 32;
        const float* src = Wh + (size_t)(r0 + row) * FO_ + cs;
        #pragma unroll
        for (int i = 0; i < 8; ++i) {
            f32x4 v = *(const f32x4*)(src + i * 4);
            #pragma unroll
            for (int u2 = 0; u2 < 4; ++u2)
                lds[row][cs + i * 4 + u2] = __float2bfloat16(v[u2]);
        }
    }
    __syncthreads();
    {
        int o = t >> 1, nh = (t & 1) * 32;
        int bb = r0 >> 12, nn = r0 & 4095;
        __hip_bfloat16* dst = WhT + ((size_t)bb * FO_ + o) * N_ + nn + nh;
        __hip_bfloat16 tmp[32];
        #pragma unroll
        for (int i = 0; i < 32; ++i) tmp[i] = lds[nh + i][o];
        #pragma unroll
        for (int i = 0; i < 4; ++i) {
            s16x8 v; __builtin_memcpy(&v, tmp + i * 8, 16);
            *(s16x8*)(dst + i * 8) = v;
        }
    }
}

// ---------------- K2: per-row src/dst + packed {e1,e2} bf16 table -------
__global__ __launch_bounds__(256) void k2_vec(
    const float* __restrict__ Wh, const float* __restrict__ aw,
    const float* __restrict__ ab, float* __restrict__ srcv,
    float* __restrict__ dstbv, unsigned* __restrict__ auxp)
{
    const int w = threadIdx.x >> 6, l = threadIdx.x & 63;
    const int r = blockIdx.x * 4 + w;                    // 0..16383
    const float2 wh = *(const float2*)(Wh + (size_t)r * FO_ + l * 2);
    const float2 as = *(const float2*)(aw + l * 2);
    const float2 ad = *(const float2*)(aw + FO_ + l * 2);
    float sp  = wh.x * as.x + wh.y * as.y;
    float dpv = wh.x * ad.x + wh.y * ad.y;
    #pragma unroll
    for (int off = 32; off >= 1; off >>= 1) {
        sp  += __shfl_xor(sp, off);
        dpv += __shfl_xor(dpv, off);
    }
    if (l == 0) {
        srcv[r] = sp;
        float db = dpv + ab[0];                          // dst_j + a_b
        dstbv[r] = db;
        auxp[r] = pkbf(__expf(db), __expf(0.01f * db));  // lo=e1, hi=e2
    }
}

// ---------------- K2b: per-batch max of dstbv ---------------------------
__global__ __launch_bounds__(256) void k2b_max(
    const float* __restrict__ dstbv, float* __restrict__ maxv)
{
    const int b = blockIdx.x;
    const int t = threadIdx.x, w = t >> 6, l = t & 63;
    float m = -3.4e38f;
    for (int i = t; i < N_; i += 256) m = fmaxf(m, dstbv[b * N_ + i]);
    #pragma unroll
    for (int off = 32; off >= 1; off >>= 1) m = fmaxf(m, __shfl_xor(m, off));
    __shared__ float red[4];
    if (l == 0) red[w] = m;
    __syncthreads();
    if (t == 0) maxv[b] = fmaxf(fmaxf(red[0], red[1]), fmaxf(red[2], red[3]));
}

// ---------------- K3: bitmask softmax+PV, no LDS, no barriers -----------
// grid (256, SPLIT): x = b*64 + rowblk(64 rows); 4 waves:
//   wave w: rowgroup rg=w>>1 (32 rows, rt=2 x 16), colhalf ch=w&1 (64 o)
__global__ __launch_bounds__(256) void k3_gat(
    const u64* __restrict__ bits, const __hip_bfloat16* __restrict__ WhT,
    const float* __restrict__ srcv, const unsigned* __restrict__ auxp,
    const float* __restrict__ maxv, float* __restrict__ pacc,
    float* __restrict__ prow)
{
    const int t = threadIdx.x;
    const int w = t >> 6, l = t & 63;
    const int lr = l & 15, g = l >> 4;
    const int rg = w >> 1, ch = w & 1;
    const int b = blockIdx.x >> 6;
    const int rbase = (blockIdx.x & 63) * 64;
    const int j0 = blockIdx.y * (N_ / SPLIT);

    float C1[2], C2[2], ET[2];
    int row[2];
    {
        const float mdb = maxv[b];
        #pragma unroll
        for (int rt = 0; rt < 2; ++rt) {
            row[rt] = rbase + rg * 32 + rt * 16 + lr;
            float s = srcv[b * N_ + row[rt]];
            float eub = s + mdb;
            float m = fmaxf(eub, 0.01f * eub);           // >= row max of LR(e)
            C1[rt] = __expf(s - m);
            C2[rt] = __expf(0.01f * s - m);
            ET[rt] = __expf(-s);                         // e1>=ET <=> e>=0
        }
    }

    const short* wp = (const short*)WhT +
                      ((size_t)b * FO_ + ch * 64 + lr) * N_ + j0 + g * 8;
    const unsigned* axp = auxp + (size_t)b * N_ + j0 + g * 8;
    const u64* bp0 = bits + ((size_t)b * N_ + row[0]) * 64 + (j0 >> 6);
    const u64* bp1 = bits + ((size_t)b * N_ + row[1]) * 64 + (j0 >> 6);

    f32x4 acc[2][4];
    f32x4 accl[2] = {(f32x4)0.f, (f32x4)0.f};
    #pragma unroll
    for (int rt = 0; rt < 2; ++rt)
        #pragma unroll
        for (int ot = 0; ot < 4; ++ot) acc[rt][ot] = (f32x4)0.f;
    s16x8 ones;
    { union { s16x8 v; unsigned u[4]; } o;
      o.u[0] = o.u[1] = o.u[2] = o.u[3] = 0x3F803F80u; ones = o.v; }

    // depth-1 register prefetch
    s16x8 Bc[4];
    #pragma unroll
    for (int ot = 0; ot < 4; ++ot) Bc[ot] = *(const s16x8*)(wp + ot * 16 * N_);
    uint4 Ac0 = *(const uint4*)(axp);
    uint4 Ac1 = *(const uint4*)(axp + 4);
    u64 bv0 = bp0[0], bv1 = bp1[0];

    #pragma unroll 2
    for (int s = 0; s < NSTEPS; ++s) {
        const int sn = (s + 1 < NSTEPS) ? s + 1 : s;
        s16x8 Bn[4];
        #pragma unroll
        for (int ot = 0; ot < 4; ++ot)
            Bn[ot] = *(const s16x8*)(wp + ot * 16 * N_ + sn * 32);
        uint4 An0 = *(const uint4*)(axp + sn * 32);
        uint4 An1 = *(const uint4*)(axp + sn * 32 + 4);
        u64 bn0 = bp0[sn >> 1], bn1 = bp1[sn >> 1];

        const unsigned sh = g * 8 + ((s & 1) << 5);
        const unsigned m0 = (unsigned)(bv0 >> sh) & 0xFFu;
        const unsigned m1 = (unsigned)(bv1 >> sh) & 0xFFu;
        unsigned ax[8] = {Ac0.x, Ac0.y, Ac0.z, Ac0.w, Ac1.x, Ac1.y, Ac1.z, Ac1.w};
        float p0[8], p1[8];
        #pragma unroll
        for (int e = 0; e < 8; ++e) {
            float e1f = __uint_as_float(ax[e] << 16);
            float e2f = __uint_as_float(ax[e] & 0xffff0000u);
            float v0 = (e1f >= ET[0]) ? C1[0] * e1f : C2[0] * e2f;
            p0[e] = ((m0 >> e) & 1u) ? v0 : 0.f;
            float v1 = (e1f >= ET[1]) ? C1[1] * e1f : C2[1] * e2f;
            p1[e] = ((m1 >> e) & 1u) ? v1 : 0.f;
        }
        union { s16x8 v; unsigned u[4]; } af0, af1;
        af0.u[0] = pkbf(p0[0], p0[1]); af0.u[1] = pkbf(p0[2], p0[3]);
        af0.u[2] = pkbf(p0[4], p0[5]); af0.u[3] = pkbf(p0[6], p0[7]);
        af1.u[0] = pkbf(p1[0], p1[1]); af1.u[1] = pkbf(p1[2], p1[3]);
        af1.u[2] = pkbf(p1[4], p1[5]); af1.u[3] = pkbf(p1[6], p1[7]);

        if (ch == 0) {
            accl[0] = __builtin_amdgcn_mfma_f32_16x16x32_bf16(af0.v, ones, accl[0], 0, 0, 0);
            accl[1] = __builtin_amdgcn_mfma_f32_16x16x32_bf16(af1.v, ones, accl[1], 0, 0, 0);
        }
        #pragma unroll
        for (int ot = 0; ot < 4; ++ot) {
            acc[0][ot] = __builtin_amdgcn_mfma_f32_16x16x32_bf16(af0.v, Bc[ot], acc[0][ot], 0, 0, 0);
            acc[1][ot] = __builtin_amdgcn_mfma_f32_16x16x32_bf16(af1.v, Bc[ot], acc[1][ot], 0, 0, 0);
        }
        #pragma unroll
        for (int ot = 0; ot < 4; ++ot) Bc[ot] = Bn[ot];
        Ac0 = An0; Ac1 = An1; bv0 = bn0; bv1 = bn1;
    }

    const size_t sb = (size_t)blockIdx.y * ((size_t)NROWS * FO_);
    #pragma unroll
    for (int rt = 0; rt < 2; ++rt) {
        #pragma unroll
        for (int kk = 0; kk < 4; ++kk) {
            int grow = b * N_ + rbase + rg * 32 + rt * 16 + g * 4 + kk;
            float* pp = pacc + sb + (size_t)grow * FO_ + ch * 64 + lr;
            #pragma unroll
            for (int ot = 0; ot < 4; ++ot)
                pp[ot * 16] = acc[rt][ot][kk];
            if (ch == 0)
                prow[blockIdx.y * NROWS + grow] = accl[rt][kk];
        }
    }
}

// ---------------- K4: combine split partials + normalize ----------------
__global__ __launch_bounds__(256) void k4_comb(
    const float* __restrict__ pacc, const float* __restrict__ prow,
    float* __restrict__ out)
{
    const int idx = blockIdx.x * 256 + threadIdx.x;      // 2,097,152
    const int grow = idx >> 7;
    float s = 0.f, rs = 0.f;
    #pragma unroll
    for (int si = 0; si < SPLIT; ++si) {
        s  += pacc[(size_t)si * ((size_t)NROWS * FO_) + idx];
        rs += prow[si * NROWS + grow];
    }
    out[idx] = s / rs;
}

extern "C" void kernel_launch(void* const* d_in, const int* in_sizes, int n_in,
                              void* d_out, int out_size, void* d_ws, size_t ws_size,
                              hipStream_t stream)
{
    const float* h  = (const float*)d_in[0];
    const int* adj  = (const int*)d_in[1];
    const float* Ww = (const float*)d_in[2];
    const float* Wb = (const float*)d_in[3];
    const float* aw = (const float*)d_in[4];
    const float* ab = (const float*)d_in[5];
    float* out = (float*)d_out;

    char* wsb = (char*)d_ws;                             // ws_size ~1 GB
    float* pacc          = (float*)wsb;                               // 32 MB
    float* Wh            = (float*)(wsb + 33554432u);                 // 8 MB
    __hip_bfloat16* WhT  = (__hip_bfloat16*)(wsb + 41943040u);        // 4 MB
    u64* bits            = (u64*)(wsb + 46137344u);                   // 8 MB
    char* aux            = wsb + 54525952u;
    float* srcv          = (float*)(aux);
    float* dstbv         = (float*)(aux + (64u << 10));
    unsigned* auxp       = (unsigned*)(aux + (128u << 10));
    __hip_bfloat16* whi  = (__hip_bfloat16*)(aux + (192u << 10));
    __hip_bfloat16* wlo  = (__hip_bfloat16*)(aux + (256u << 10));
    float* maxv          = (float*)(aux + (320u << 10));
    float* prow          = (float*)(aux + (384u << 10));              // 256 KB

    k_adjb<<<4096, 256, 0, stream>>>(adj, bits);
    k0_packw<<<128, 256, 0, stream>>>(Ww, whi, wlo);
    k1_wh<<<1024, 256, 0, stream>>>(h, whi, wlo, Wb, Wh);
    k1t<<<256, 256, 0, stream>>>(Wh, WhT);
    k2_vec<<<4096, 256, 0, stream>>>(Wh, aw, ab, srcv, dstbv, auxp);
    k2b_max<<<4, 256, 0, stream>>>(dstbv, maxv);
    dim3 g3(NB_ * 64, SPLIT);
    k3_gat<<<g3, 256, 0, stream>>>(bits, WhT, srcv, auxp, maxv, pacc, prow);
    k4_comb<<<8192, 256, 0, stream>>>(pacc, prow, out);
}

// Round 6
// 165.493 us; speedup vs baseline: 1.2412x; 1.2412x over previous
//
#include <hip/hip_runtime.h>
#include <hip/hip_bf16.h>

typedef __attribute__((ext_vector_type(4))) float f32x4;
typedef __attribute__((ext_vector_type(8))) short s16x8;
typedef unsigned long long u64;

#define NB_ 4
#define N_ 4096
#define FI_ 256
#define FO_ 128
#define NROWS 16384       // NB_ * N_
#define SPLIT 4
#define NSTEPS ((N_ / SPLIT) / 32)   // 32 steps of 32 cols

// pack two f32 -> one u32 of 2 bf16 (RNE), first arg in low half
__device__ __forceinline__ unsigned pkbf(float a, float b) {
    __hip_bfloat162 t = __float22bfloat162_rn(make_float2(a, b));
    unsigned r; __builtin_memcpy(&r, &t, 4); return r;
}

// ---------------- K0: pack W into bf16 hi/lo ----------------------------
__global__ __launch_bounds__(256) void k0_packw(
    const float* __restrict__ Ww, __hip_bfloat16* __restrict__ whi,
    __hip_bfloat16* __restrict__ wlo)
{
    int idx = blockIdx.x * 256 + threadIdx.x;           // 32768 elems
    float v = Ww[idx];
    __hip_bfloat16 hi = __float2bfloat16(v);
    whi[idx] = hi;
    wlo[idx] = __float2bfloat16(v - __bfloat162float(hi));
}

// ---------------- K1: Wh GEMM + fused epilogue --------------------------
// 1024 blocks x 16 rows. Produces WhT (bf16 [b][o][n]), srcv, dstbv, auxp.
// Wh f32 never goes to HBM.
__global__ __launch_bounds__(256) void k1_wh(
    const float* __restrict__ h, const __hip_bfloat16* __restrict__ whi,
    const __hip_bfloat16* __restrict__ wlo, const float* __restrict__ Wb,
    const float* __restrict__ aw, const float* __restrict__ ab,
    __hip_bfloat16* __restrict__ WhT, float* __restrict__ srcv,
    float* __restrict__ dstbv, unsigned* __restrict__ auxp)
{
    __shared__ float lds[16][132];
    const int tid = threadIdx.x;
    const int w = tid >> 6, l = tid & 63;
    const int lr = l & 15, g = l >> 4;
    const int r0 = blockIdx.x * 16;
    const float* hp = h + (size_t)(r0 + lr) * FI_ + g * 8;

    f32x4 acc[2] = {(f32x4)0.f, (f32x4)0.f};

    #pragma unroll
    for (int kt = 0; kt < 8; ++kt) {
        f32x4 x0 = *(const f32x4*)(hp + kt * 32);
        f32x4 x1 = *(const f32x4*)(hp + kt * 32 + 4);
        float xx[8];
        #pragma unroll
        for (int t = 0; t < 4; ++t) { xx[t] = x0[t]; xx[t + 4] = x1[t]; }
        union { s16x8 v; unsigned u[4]; } ahi, alo;
        #pragma unroll
        for (int t = 0; t < 4; ++t) {
            float a0 = xx[2 * t], a1 = xx[2 * t + 1];
            unsigned uh = pkbf(a0, a1);
            ahi.u[t] = uh;
            float h0f = __uint_as_float(uh << 16);
            float h1f = __uint_as_float(uh & 0xffff0000u);
            alo.u[t] = pkbf(a0 - h0f, a1 - h1f);
        }
        #pragma unroll
        for (int c = 0; c < 2; ++c) {
            const int o = w * 32 + c * 16 + lr;
            s16x8 bh = *(const s16x8*)(whi + (size_t)o * FI_ + kt * 32 + g * 8);
            s16x8 bl = *(const s16x8*)(wlo + (size_t)o * FI_ + kt * 32 + g * 8);
            acc[c] = __builtin_amdgcn_mfma_f32_16x16x32_bf16(ahi.v, bh, acc[c], 0, 0, 0);
            acc[c] = __builtin_amdgcn_mfma_f32_16x16x32_bf16(alo.v, bh, acc[c], 0, 0, 0);
            acc[c] = __builtin_amdgcn_mfma_f32_16x16x32_bf16(ahi.v, bl, acc[c], 0, 0, 0);
        }
    }

    // C/D layout: col=lane&15, row=(lane>>4)*4+reg  [m89]
    #pragma unroll
    for (int c = 0; c < 2; ++c) {
        int col = w * 32 + c * 16 + lr;
        float wb = Wb[col];
        #pragma unroll
        for (int kk = 0; kk < 4; ++kk)
            lds[g * 4 + kk][col] = acc[c][kk] + wb;
    }
    __syncthreads();

    // (a) WhT bf16 [b][o][n]: thread -> (o = t>>1, half = t&1), 16-B store
    {
        const int o = tid >> 1, half = tid & 1;
        const int bb = r0 >> 12, nn = (r0 & 4095) + half * 8;
        union { s16x8 v; unsigned u[4]; } af;
        #pragma unroll
        for (int i = 0; i < 4; ++i)
            af.u[i] = pkbf(lds[half * 8 + 2 * i][o], lds[half * 8 + 2 * i + 1][o]);
        *(s16x8*)(WhT + ((size_t)bb * FO_ + o) * N_ + nn) = af.v;
    }

    // (b) per-row src/dst dots + exp tables
    {
        const int row = tid >> 4, seg = tid & 15;
        float sp = 0.f, dp = 0.f;
        #pragma unroll
        for (int i = 0; i < 8; ++i) {
            float v = lds[row][seg * 8 + i];
            sp += v * aw[seg * 8 + i];
            dp += v * aw[FO_ + seg * 8 + i];
        }
        #pragma unroll
        for (int off = 8; off >= 1; off >>= 1) {
            sp += __shfl_xor(sp, off);
            dp += __shfl_xor(dp, off);
        }
        if (seg == 0) {
            int r = r0 + row;
            srcv[r] = sp;
            float db = dp + ab[0];
            dstbv[r] = db;
            auxp[r] = pkbf(__expf(db), __expf(0.01f * db));   // lo=e1, hi=e2
        }
    }
}

// ---------------- K2b: per-batch max of dstbv ---------------------------
__global__ __launch_bounds__(256) void k2b_max(
    const float* __restrict__ dstbv, float* __restrict__ maxv)
{
    const int b = blockIdx.x;
    const int t = threadIdx.x, w = t >> 6, l = t & 63;
    float m = -3.4e38f;
    for (int i = t; i < N_; i += 256) m = fmaxf(m, dstbv[b * N_ + i]);
    #pragma unroll
    for (int off = 32; off >= 1; off >>= 1) m = fmaxf(m, __shfl_xor(m, off));
    __shared__ float red[4];
    if (l == 0) red[w] = m;
    __syncthreads();
    if (t == 0) maxv[b] = fmaxf(fmaxf(red[0], red[1]), fmaxf(red[2], red[3]));
}

// ---------------- K3: single-pass adj stream + softmax + PV -------------
// grid (128, SPLIT): x = b*32 + rowblk(128 rows); 4 waves x 32 rows x 128 o
// p_ij = max(C1_i*e1_j, C2_i*e2_j) masked by adj>0  (exact LeakyReLU softmax)
__global__ __launch_bounds__(256, 2) void k3_gat(
    const int* __restrict__ adj, const __hip_bfloat16* __restrict__ WhT,
    const float* __restrict__ srcv, const unsigned* __restrict__ auxp,
    const float* __restrict__ maxv, float* __restrict__ pacc,
    float* __restrict__ prow)
{
    const int t = threadIdx.x;
    const int w = t >> 6, l = t & 63;
    const int lr = l & 15, g = l >> 4;
    const int b = blockIdx.x >> 5;
    const int rbase = (blockIdx.x & 31) * 128 + w * 32;  // wave row base (in batch)
    const int j0 = blockIdx.y * (N_ / SPLIT);

    float C1r[2], C2r[2];
    int row[2];
    {
        const float mdb = maxv[b];
        #pragma unroll
        for (int rt = 0; rt < 2; ++rt) {
            row[rt] = rbase + rt * 16 + lr;
            float s = srcv[b * N_ + row[rt]];
            float eub = s + mdb;
            float m = fmaxf(eub, 0.01f * eub);           // >= row max of LR(e)
            C1r[rt] = __expf(s - m);
            C2r[rt] = __expf(0.01f * s - m);
        }
    }

    const int* adjp0 = adj + ((size_t)(b * N_ + row[0])) * N_ + j0 + g * 8;
    const int* adjp1 = adj + ((size_t)(b * N_ + row[1])) * N_ + j0 + g * 8;
    const unsigned* axp = auxp + (size_t)b * N_ + j0 + g * 8;
    const short* wbase = (const short*)WhT + ((size_t)b * FO_ + lr) * N_ + j0 + g * 8;

    f32x4 acc0[8], acc1[8];
    f32x4 accl0 = (f32x4)0.f, accl1 = (f32x4)0.f;
    #pragma unroll
    for (int ot = 0; ot < 8; ++ot) { acc0[ot] = (f32x4)0.f; acc1[ot] = (f32x4)0.f; }
    s16x8 ones;
    { union { s16x8 v; unsigned u[4]; } o;
      o.u[0] = o.u[1] = o.u[2] = o.u[3] = 0x3F803F80u; ones = o.v; }

    auto ldset = [&](int s, int4& A00, int4& A01, int4& A10, int4& A11,
                     uint4& X0, uint4& X1) {
        const int jc = s * 32;
        A00 = *(const int4*)(adjp0 + jc);
        A01 = *(const int4*)(adjp0 + jc + 4);
        A10 = *(const int4*)(adjp1 + jc);
        A11 = *(const int4*)(adjp1 + jc + 4);
        X0  = *(const uint4*)(axp + jc);
        X1  = *(const uint4*)(axp + jc + 4);
    };

    auto cmpute = [&](int s, const int4& A00, const int4& A01, const int4& A10,
                      const int4& A11, const uint4& X0, const uint4& X1) {
        const int jc = s * 32;
        s16x8 B[8];
        #pragma unroll
        for (int ot = 0; ot < 8; ++ot)                   // issue first: L2 latency
            B[ot] = *(const s16x8*)(wbase + (size_t)(ot * 16) * N_ + jc);

        const unsigned ax[8] = {X0.x, X0.y, X0.z, X0.w, X1.x, X1.y, X1.z, X1.w};
        const int av0[8] = {A00.x, A00.y, A00.z, A00.w, A01.x, A01.y, A01.z, A01.w};
        const int av1[8] = {A10.x, A10.y, A10.z, A10.w, A11.x, A11.y, A11.z, A11.w};
        float p0[8], p1[8];
        #pragma unroll
        for (int e = 0; e < 8; ++e) {
            float e1f = __uint_as_float(ax[e] << 16);
            float e2f = __uint_as_float(ax[e] & 0xffff0000u);
            float v0 = fmaxf(e1f * C1r[0], e2f * C2r[0]);
            float v1 = fmaxf(e1f * C1r[1], e2f * C2r[1]);
            p0[e] = (av0[e] > 0) ? v0 : 0.f;
            p1[e] = (av1[e] > 0) ? v1 : 0.f;
        }
        union { s16x8 v; unsigned u[4]; } af0, af1;
        af0.u[0] = pkbf(p0[0], p0[1]); af0.u[1] = pkbf(p0[2], p0[3]);
        af0.u[2] = pkbf(p0[4], p0[5]); af0.u[3] = pkbf(p0[6], p0[7]);
        af1.u[0] = pkbf(p1[0], p1[1]); af1.u[1] = pkbf(p1[2], p1[3]);
        af1.u[2] = pkbf(p1[4], p1[5]); af1.u[3] = pkbf(p1[6], p1[7]);

        accl0 = __builtin_amdgcn_mfma_f32_16x16x32_bf16(af0.v, ones, accl0, 0, 0, 0);
        accl1 = __builtin_amdgcn_mfma_f32_16x16x32_bf16(af1.v, ones, accl1, 0, 0, 0);
        #pragma unroll
        for (int ot = 0; ot < 8; ++ot) {
            acc0[ot] = __builtin_amdgcn_mfma_f32_16x16x32_bf16(af0.v, B[ot], acc0[ot], 0, 0, 0);
            acc1[ot] = __builtin_amdgcn_mfma_f32_16x16x32_bf16(af1.v, B[ot], acc1[ot], 0, 0, 0);
        }
    };

    int4 A00, A01, A10, A11; uint4 X0, X1;               // set A
    int4 B00, B01, B10, B11; uint4 Y0, Y1;               // set B
    ldset(0, A00, A01, A10, A11, X0, X1);

    for (int it = 0; it < NSTEPS / 2; ++it) {
        const int s0 = it * 2;
        ldset(s0 + 1, B00, B01, B10, B11, Y0, Y1);
        cmpute(s0, A00, A01, A10, A11, X0, X1);
        if (it + 1 < NSTEPS / 2)
            ldset(s0 + 2, A00, A01, A10, A11, X0, X1);
        cmpute(s0 + 1, B00, B01, B10, B11, Y0, Y1);
    }

    const size_t sb = (size_t)blockIdx.y * ((size_t)NROWS * FO_);
    #pragma unroll
    for (int rt = 0; rt < 2; ++rt) {
        #pragma unroll
        for (int kk = 0; kk < 4; ++kk) {
            int grow = b * N_ + rbase + rt * 16 + g * 4 + kk;
            float* pp = pacc + sb + (size_t)grow * FO_ + lr;
            const f32x4* a = rt == 0 ? acc0 : acc1;
            #pragma unroll
            for (int ot = 0; ot < 8; ++ot)
                pp[ot * 16] = a[ot][kk];
            prow[blockIdx.y * NROWS + grow] = (rt == 0 ? accl0 : accl1)[kk];
        }
    }
}

// ---------------- K4: combine split partials + normalize ----------------
__global__ __launch_bounds__(256) void k4_comb(
    const float* __restrict__ pacc, const float* __restrict__ prow,
    float* __restrict__ out)
{
    const int idx = blockIdx.x * 256 + threadIdx.x;      // 2,097,152
    const int grow = idx >> 7;
    float s = 0.f, rs = 0.f;
    #pragma unroll
    for (int si = 0; si < SPLIT; ++si) {
        s  += pacc[(size_t)si * ((size_t)NROWS * FO_) + idx];
        rs += prow[si * NROWS + grow];
    }
    out[idx] = s / rs;
}

extern "C" void kernel_launch(void* const* d_in, const int* in_sizes, int n_in,
                              void* d_out, int out_size, void* d_ws, size_t ws_size,
                              hipStream_t stream)
{
    const float* h  = (const float*)d_in[0];
    const int* adj  = (const int*)d_in[1];
    const float* Ww = (const float*)d_in[2];
    const float* Wb = (const float*)d_in[3];
    const float* aw = (const float*)d_in[4];
    const float* ab = (const float*)d_in[5];
    float* out = (float*)d_out;

    char* wsb = (char*)d_ws;                             // ws_size ~1 GB
    float* pacc          = (float*)wsb;                               // 32 MB
    __hip_bfloat16* WhT  = (__hip_bfloat16*)(wsb + 33554432u);        // 4 MB
    char* aux            = wsb + 37748736u;
    float* srcv          = (float*)(aux);                             // 64 KB
    float* dstbv         = (float*)(aux + (64u << 10));               // 64 KB
    unsigned* auxp       = (unsigned*)(aux + (128u << 10));           // 64 KB
    __hip_bfloat16* whi  = (__hip_bfloat16*)(aux + (192u << 10));     // 64 KB
    __hip_bfloat16* wlo  = (__hip_bfloat16*)(aux + (256u << 10));     // 64 KB
    float* maxv          = (float*)(aux + (320u << 10));              // 16 B
    float* prow          = (float*)(aux + (384u << 10));              // 256 KB

    k0_packw<<<128, 256, 0, stream>>>(Ww, whi, wlo);
    k1_wh<<<1024, 256, 0, stream>>>(h, whi, wlo, Wb, aw, ab, WhT, srcv, dstbv, auxp);
    k2b_max<<<4, 256, 0, stream>>>(dstbv, maxv);
    dim3 g3(NB_ * 32, SPLIT);
    k3_gat<<<g3, 256, 0, stream>>>(adj, WhT, srcv, auxp, maxv, pacc, prow);
    k4_comb<<<8192, 256, 0, stream>>>(pacc, prow, out);
}

// Round 7
// 144.624 us; speedup vs baseline: 1.4203x; 1.1443x over previous
//
#include <hip/hip_runtime.h>
#include <hip/hip_bf16.h>

typedef __attribute__((ext_vector_type(4))) float f32x4;
typedef __attribute__((ext_vector_type(8))) short s16x8;
typedef unsigned long long u64;

#define NB_ 4
#define N_ 4096
#define FI_ 256
#define FO_ 128
#define NROWS 16384       // NB_ * N_
#define SPLIT 4
#define JSTEP 32
#define NSTEPS ((N_ / SPLIT) / JSTEP)   // 32 steps of 32 cols

// pack two f32 -> one u32 of 2 bf16 (RNE), first arg in low half
__device__ __forceinline__ unsigned pkbf(float a, float b) {
    __hip_bfloat162 t = __float22bfloat162_rn(make_float2(a, b));
    unsigned r; __builtin_memcpy(&r, &t, 4); return r;
}

typedef __attribute__((address_space(1))) const void CGV;
typedef __attribute__((address_space(3))) void LDSV;
__device__ __forceinline__ void gload16(const void* g, void* l) {
    __builtin_amdgcn_global_load_lds((CGV*)g, (LDSV*)l, 16, 0, 0);
}

// ---------------- K0: pack W into bf16 hi/lo ----------------------------
__global__ __launch_bounds__(256) void k0_packw(
    const float* __restrict__ Ww, __hip_bfloat16* __restrict__ whi,
    __hip_bfloat16* __restrict__ wlo)
{
    int idx = blockIdx.x * 256 + threadIdx.x;           // 32768 elems
    float v = Ww[idx];
    __hip_bfloat16 hi = __float2bfloat16(v);
    whi[idx] = hi;
    wlo[idx] = __float2bfloat16(v - __bfloat162float(hi));
}

// ---------------- K1: Wh GEMM + fused epilogue --------------------------
// 1024 blocks x 16 rows. Produces WhT (bf16 [b][o][n]), srcv, dstbv, auxp.
__global__ __launch_bounds__(256) void k1_wh(
    const float* __restrict__ h, const __hip_bfloat16* __restrict__ whi,
    const __hip_bfloat16* __restrict__ wlo, const float* __restrict__ Wb,
    const float* __restrict__ aw, const float* __restrict__ ab,
    __hip_bfloat16* __restrict__ WhT, float* __restrict__ srcv,
    float* __restrict__ dstbv, unsigned* __restrict__ auxp)
{
    __shared__ float lds[16][132];
    const int tid = threadIdx.x;
    const int w = tid >> 6, l = tid & 63;
    const int lr = l & 15, g = l >> 4;
    const int r0 = blockIdx.x * 16;
    const float* hp = h + (size_t)(r0 + lr) * FI_ + g * 8;

    f32x4 acc[2] = {(f32x4)0.f, (f32x4)0.f};

    #pragma unroll
    for (int kt = 0; kt < 8; ++kt) {
        f32x4 x0 = *(const f32x4*)(hp + kt * 32);
        f32x4 x1 = *(const f32x4*)(hp + kt * 32 + 4);
        float xx[8];
        #pragma unroll
        for (int t = 0; t < 4; ++t) { xx[t] = x0[t]; xx[t + 4] = x1[t]; }
        union { s16x8 v; unsigned u[4]; } ahi, alo;
        #pragma unroll
        for (int t = 0; t < 4; ++t) {
            float a0 = xx[2 * t], a1 = xx[2 * t + 1];
            unsigned uh = pkbf(a0, a1);
            ahi.u[t] = uh;
            float h0f = __uint_as_float(uh << 16);
            float h1f = __uint_as_float(uh & 0xffff0000u);
            alo.u[t] = pkbf(a0 - h0f, a1 - h1f);
        }
        #pragma unroll
        for (int c = 0; c < 2; ++c) {
            const int o = w * 32 + c * 16 + lr;
            s16x8 bh = *(const s16x8*)(whi + (size_t)o * FI_ + kt * 32 + g * 8);
            s16x8 bl = *(const s16x8*)(wlo + (size_t)o * FI_ + kt * 32 + g * 8);
            acc[c] = __builtin_amdgcn_mfma_f32_16x16x32_bf16(ahi.v, bh, acc[c], 0, 0, 0);
            acc[c] = __builtin_amdgcn_mfma_f32_16x16x32_bf16(alo.v, bh, acc[c], 0, 0, 0);
            acc[c] = __builtin_amdgcn_mfma_f32_16x16x32_bf16(ahi.v, bl, acc[c], 0, 0, 0);
        }
    }

    #pragma unroll
    for (int c = 0; c < 2; ++c) {
        int col = w * 32 + c * 16 + lr;
        float wb = Wb[col];
        #pragma unroll
        for (int kk = 0; kk < 4; ++kk)
            lds[g * 4 + kk][col] = acc[c][kk] + wb;
    }
    __syncthreads();

    {   // WhT bf16 [b][o][n]
        const int o = tid >> 1, half = tid & 1;
        const int bb = r0 >> 12, nn = (r0 & 4095) + half * 8;
        union { s16x8 v; unsigned u[4]; } af;
        #pragma unroll
        for (int i = 0; i < 4; ++i)
            af.u[i] = pkbf(lds[half * 8 + 2 * i][o], lds[half * 8 + 2 * i + 1][o]);
        *(s16x8*)(WhT + ((size_t)bb * FO_ + o) * N_ + nn) = af.v;
    }

    {   // per-row src/dst dots + exp tables
        const int row = tid >> 4, seg = tid & 15;
        float sp = 0.f, dp = 0.f;
        #pragma unroll
        for (int i = 0; i < 8; ++i) {
            float v = lds[row][seg * 8 + i];
            sp += v * aw[seg * 8 + i];
            dp += v * aw[FO_ + seg * 8 + i];
        }
        #pragma unroll
        for (int off = 8; off >= 1; off >>= 1) {
            sp += __shfl_xor(sp, off);
            dp += __shfl_xor(dp, off);
        }
        if (seg == 0) {
            int r = r0 + row;
            srcv[r] = sp;
            float db = dp + ab[0];
            dstbv[r] = db;
            auxp[r] = pkbf(__expf(db), __expf(0.01f * db));   // lo=e1, hi=e2
        }
    }
}

// ---------------- K2b: per-batch max of dstbv ---------------------------
__global__ __launch_bounds__(256) void k2b_max(
    const float* __restrict__ dstbv, float* __restrict__ maxv)
{
    const int b = blockIdx.x;
    const int t = threadIdx.x, w = t >> 6, l = t & 63;
    float m = -3.4e38f;
    for (int i = t; i < N_; i += 256) m = fmaxf(m, dstbv[b * N_ + i]);
    #pragma unroll
    for (int off = 32; off >= 1; off >>= 1) m = fmaxf(m, __shfl_xor(m, off));
    __shared__ float red[4];
    if (l == 0) red[w] = m;
    __syncthreads();
    if (t == 0) maxv[b] = fmaxf(fmaxf(red[0], red[1]), fmaxf(red[2], red[3]));
}

// ---------------- K3: adj stream + softmax + PV, LDS-B pipeline ---------
// grid (256, SPLIT): x = b*64 + rowblk; block = 4 waves x 16 rows, all 128 o
// B (WhT j-tile) staged fragment-major in LDS via global_load_lds (T14:
// issue-early), shared by 4 waves. adj/aux in register double-buffer.
__global__ __launch_bounds__(256, 4) void k3_gat(
    const int* __restrict__ adj, const __hip_bfloat16* __restrict__ WhT,
    const float* __restrict__ srcv, const unsigned* __restrict__ auxp,
    const float* __restrict__ maxv, float* __restrict__ pacc,
    float* __restrict__ prow)
{
    __shared__ __hip_bfloat16 bbuf[2][4096];   // 2 x 8 KB, fragment-major
    __shared__ float rsum[64];

    const int t = threadIdx.x;
    const int w = t >> 6, l = t & 63;
    const int lr = l & 15, g = l >> 4;
    const int b = blockIdx.x >> 6;
    const int rbase = (blockIdx.x & 63) * 64 + w * 16;   // wave's 16-row base
    const int myrow = rbase + lr;
    const int j0 = blockIdx.y * (N_ / SPLIT);

    float C1, C2;
    {
        float s = srcv[b * N_ + myrow];
        float eub = s + maxv[b];
        float m = fmaxf(eub, 0.01f * eub);               // >= row max of LR(e)
        C1 = __expf(s - m);
        C2 = __expf(0.01f * s - m);
    }

    const int* adjp = adj + ((size_t)(b * N_ + myrow)) * N_ + j0 + g * 8;
    const unsigned* axp = auxp + (size_t)b * N_ + j0 + g * 8;
    // stage source: slot = i*256 + t -> frag ot = slot>>6 (0..7), lane l
    const short* wsrc = (const short*)WhT +
                        ((size_t)b * FO_ + (w & 3) * 16 + lr) * N_ + j0 + g * 8;

    f32x4 acc[8];
    #pragma unroll
    for (int ot = 0; ot < 8; ++ot) acc[ot] = (f32x4)0.f;
    float rs = 0.f;

    auto stage = [&](int bi, int s) {
        const int jb = s * JSTEP;
        // slot i*256+t: ot = i*4 + w; o = ot*16 + lr; j = jb + g*8
        gload16(wsrc + (size_t)((0 * 4) * 16) * N_ + jb, &bbuf[bi][(0 * 256 + w * 64) * 8]);
        gload16(wsrc + (size_t)((1 * 4) * 16) * N_ + jb, &bbuf[bi][(1 * 256 + w * 64) * 8]);
    };

    int4 a0c, a1c; uint4 xc0, xc1;
    stage(0, 0);
    a0c = *(const int4*)(adjp);
    a1c = *(const int4*)(adjp + 4);
    xc0 = *(const uint4*)(axp);
    xc1 = *(const uint4*)(axp + 4);
    __syncthreads();
    int cur = 0;

    for (int s = 0; s < NSTEPS; ++s) {
        int4 a0n = {0,0,0,0}, a1n = {0,0,0,0};
        uint4 xn0 = {0,0,0,0}, xn1 = {0,0,0,0};
        if (s + 1 < NSTEPS) {                            // issue-early (T14)
            stage(cur ^ 1, s + 1);
            const int jn = (s + 1) * JSTEP;
            a0n = *(const int4*)(adjp + jn);
            a1n = *(const int4*)(adjp + jn + 4);
            xn0 = *(const uint4*)(axp + jn);
            xn1 = *(const uint4*)(axp + jn + 4);
        }

        // decode P for this step
        const unsigned ax[8] = {xc0.x, xc0.y, xc0.z, xc0.w, xc1.x, xc1.y, xc1.z, xc1.w};
        const int av[8] = {a0c.x, a0c.y, a0c.z, a0c.w, a1c.x, a1c.y, a1c.z, a1c.w};
        float p[8];
        #pragma unroll
        for (int e = 0; e < 8; ++e) {
            float e1f = __uint_as_float(ax[e] << 16);
            float e2f = __uint_as_float(ax[e] & 0xffff0000u);
            float v = fmaxf(e1f * C1, e2f * C2);         // exact LR softmax p
            p[e] = (av[e] > 0) ? v : 0.f;
            rs += p[e];
        }
        union { s16x8 v; unsigned u[4]; } af;
        af.u[0] = pkbf(p[0], p[1]); af.u[1] = pkbf(p[2], p[3]);
        af.u[2] = pkbf(p[4], p[5]); af.u[3] = pkbf(p[6], p[7]);

        #pragma unroll
        for (int ot = 0; ot < 8; ++ot) {
            s16x8 Bf = *(const s16x8*)&bbuf[cur][(ot * 64 + l) * 8];
            acc[ot] = __builtin_amdgcn_mfma_f32_16x16x32_bf16(af.v, Bf, acc[ot], 0, 0, 0);
        }

        __syncthreads();   // stage(s+1) had the whole compute to fly
        a0c = a0n; a1c = a1n; xc0 = xn0; xc1 = xn1;
        cur ^= 1;
    }

    // row-sum: reduce over g-groups, park in LDS for C-layout epilogue
    rs += __shfl_xor(rs, 16);
    rs += __shfl_xor(rs, 32);
    if (g == 0) rsum[w * 16 + lr] = rs;
    __syncthreads();

    const size_t sb = (size_t)blockIdx.y * ((size_t)NROWS * FO_);
    #pragma unroll
    for (int kk = 0; kk < 4; ++kk) {
        int grow = b * N_ + rbase + g * 4 + kk;
        float* pp = pacc + sb + (size_t)grow * FO_ + lr;
        #pragma unroll
        for (int ot = 0; ot < 8; ++ot)
            pp[ot * 16] = acc[ot][kk];
        if (lr == 0)
            prow[blockIdx.y * NROWS + grow] = rsum[w * 16 + g * 4 + kk];
    }
}

// ---------------- K4: combine split partials + normalize ----------------
__global__ __launch_bounds__(256) void k4_comb(
    const float* __restrict__ pacc, const float* __restrict__ prow,
    float* __restrict__ out)
{
    const int idx = blockIdx.x * 256 + threadIdx.x;      // 2,097,152
    const int grow = idx >> 7;
    float s = 0.f, rs = 0.f;
    #pragma unroll
    for (int si = 0; si < SPLIT; ++si) {
        s  += pacc[(size_t)si * ((size_t)NROWS * FO_) + idx];
        rs += prow[si * NROWS + grow];
    }
    out[idx] = s / rs;
}

extern "C" void kernel_launch(void* const* d_in, const int* in_sizes, int n_in,
                              void* d_out, int out_size, void* d_ws, size_t ws_size,
                              hipStream_t stream)
{
    const float* h  = (const float*)d_in[0];
    const int* adj  = (const int*)d_in[1];
    const float* Ww = (const float*)d_in[2];
    const float* Wb = (const float*)d_in[3];
    const float* aw = (const float*)d_in[4];
    const float* ab = (const float*)d_in[5];
    float* out = (float*)d_out;

    char* wsb = (char*)d_ws;                             // ws_size ~1 GB
    float* pacc          = (float*)wsb;                               // 32 MB
    __hip_bfloat16* WhT  = (__hip_bfloat16*)(wsb + 33554432u);        // 4 MB
    char* aux            = wsb + 37748736u;
    float* srcv          = (float*)(aux);                             // 64 KB
    float* dstbv         = (float*)(aux + (64u << 10));               // 64 KB
    unsigned* auxp       = (unsigned*)(aux + (128u << 10));           // 64 KB
    __hip_bfloat16* whi  = (__hip_bfloat16*)(aux + (192u << 10));     // 64 KB
    __hip_bfloat16* wlo  = (__hip_bfloat16*)(aux + (256u << 10));     // 64 KB
    float* maxv          = (float*)(aux + (320u << 10));              // 16 B
    float* prow          = (float*)(aux + (384u << 10));              // 256 KB

    k0_packw<<<128, 256, 0, stream>>>(Ww, whi, wlo);
    k1_wh<<<1024, 256, 0, stream>>>(h, whi, wlo, Wb, aw, ab, WhT, srcv, dstbv, auxp);
    k2b_max<<<4, 256, 0, stream>>>(dstbv, maxv);
    dim3 g3(NB_ * 64, SPLIT);
    k3_gat<<<g3, 256, 0, stream>>>(adj, WhT, srcv, auxp, maxv, pacc, prow);
    k4_comb<<<8192, 256, 0, stream>>>(pacc, prow, out);
}